// Round 12
// baseline (224.806 us; speedup 1.0000x reference)
//
#include <hip/hip_runtime.h>

#define BB 8
#define C 64
#define HH 128
#define WW 128
#define HW (HH*WW)

#define TS 72        // LDS channel stride (ushorts) for conv0 halo tile
#define NPX 324      // 18*18 halo tile pixels
#define NCALL 41     // ceil(324/8) staging calls of 8 px

typedef __attribute__((ext_vector_type(8))) short short8;
typedef __attribute__((ext_vector_type(4))) unsigned short us4;
typedef __attribute__((ext_vector_type(4))) float f32x4;

__device__ inline unsigned short f2bf(float f) {
    union { float f; unsigned u; } v; v.f = f;
    unsigned r = v.u + 0x7fff + ((v.u >> 16) & 1);   // RNE
    return (unsigned short)(r >> 16);
}
__device__ inline float bf2f(unsigned short h) {
    union { unsigned u; float f; } v; v.u = ((unsigned)h) << 16;
    return v.f;
}

// async global->LDS, 16B per lane, LDS dest = uniform base + lane*16
__device__ __forceinline__ void gload16(const void* g, void* l) {
    __builtin_amdgcn_global_load_lds(
        (const __attribute__((address_space(1))) void*)g,
        (__attribute__((address_space(3))) void*)l, 16, 0, 0);
}

// ---------------------------------------------------------------------------
// Stage an 18x18 bf16-NHWC halo tile into LINEAR LDS [px][64] via
// global_load_lds (8 waves), bank swizzle applied on the SOURCE side:
// LDS slot s of pixel px holds channel octet (s ^ (px&7)). Readers apply
// the same XOR. OOB lanes fetch from a 16B zero page.
// ---------------------------------------------------------------------------
__device__ __forceinline__ void stage_tile_nhwc8(
    const unsigned short* __restrict__ in, unsigned short* tile,
    const unsigned short* __restrict__ zpad,
    const int b, const int h0, const int w0, const int t)
{
    const int wv = t >> 6, ln = t & 63;
    const int pxo = ln >> 3, s = ln & 7;
    for (int call = wv; call < NCALL; call += 8) {
        const int px = call*8 + pxo;
        const int o  = s ^ (px & 7);
        const int th = px / 18, tw = px - th*18;
        const int gh = h0 + th - 1, gw = w0 + tw - 1;
        const unsigned short* src = zpad;
        if (px < NPX && (unsigned)gh < HH && (unsigned)gw < WW)
            src = &in[((size_t)(b*HW) + gh*WW + gw)*C + o*8];
        gload16(src, &tile[call*8*64]);     // wave-uniform LDS base
    }
}

// ---------------------------------------------------------------------------
// Prep: wb[p][oc][ci] (B^T bf16) for conv0/convf; wb3[j][oc][k] bf16 and
// b3r[j][oc] for the dynamic-filter GEMM; zero m and the 16B zero page.
// ---------------------------------------------------------------------------
__global__ __launch_bounds__(256) void prep_kernel(
    const float* __restrict__ w0, const float* __restrict__ wf,
    const float* __restrict__ w3, const float* __restrict__ b3,
    unsigned short* __restrict__ wb0, unsigned short* __restrict__ wbf,
    unsigned short* __restrict__ wb3, float* __restrict__ b3r,
    float* __restrict__ m, unsigned short* __restrict__ zpad)
{
    const int t = blockIdx.x * 256 + threadIdx.x;
    for (int i = t; i < C*C*9; i += 128*256) {
        int p = i % 9; int rest = i / 9; int ci = rest % C; int oc = rest / C;
        wb0[(p*C + oc)*C + ci] = f2bf(w0[i]);
        wbf[(p*C + oc)*C + ci] = f2bf(wf[i]);
    }
    for (int i = t; i < 9*C*C; i += 128*256) {       // dst index: ((j*64+oc)*64+k)
        int j = i >> 12, oc = (i >> 6) & 63, k = i & 63;
        wb3[i] = f2bf(w3[(oc*9 + j)*C + k]);
    }
    for (int i = t; i < 9*C; i += 128*256) {         // b3r[j*64+oc] = b3[oc*9+j]
        int j = i >> 6, oc = i & 63;
        b3r[i] = b3[oc*9 + j];
    }
    for (int i = t; i < BB*C; i += 128*256) m[i] = 0.f;
    if (t < 128) zpad[t] = 0;
}

// ---------------------------------------------------------------------------
// conv0: MFMA implicit-GEMM 3x3. 16x16 px tile, 512 threads (8 waves),
// wave = (wr = row-quad, ng = oc-half) [layout verified round 2/3].
// (512,2): VGPR cap 128 -> 2 blocks/CU = 16 waves/CU (round 3 evidence:
// convs at this point ran <44 us with no visible spill).
// in = x fp32 NCHW (gather staging, TS=72) -> x0 bf16 NHWC (+bias) + mean->m
// ---------------------------------------------------------------------------
__global__ __launch_bounds__(512, 2) void conv0_kernel(
    const float* __restrict__ in,
    const unsigned short* __restrict__ wb,   // [9][64][64] bf16 (B^T)
    const float* __restrict__ bias,
    unsigned short* __restrict__ outp,
    float* __restrict__ m)
{
    __shared__ __align__(16) unsigned short tile[NPX*TS];  // 46.7 KB
    __shared__ __align__(16) float sred[2][2][4][16];      // 1 KB (mean reduce)
    const int b  = blockIdx.z;
    const int h0 = blockIdx.y * 16;
    const int w0 = blockIdx.x * 16;
    const int t  = threadIdx.x;

    {
        const int pxi = t & 63, g = t >> 6;          // g = channel octet (per wave)
        for (int px = pxi; px < NPX; px += 64) {
            int th = px / 18, tw = px - th*18;
            int gh = h0 + th - 1, gw = w0 + tw - 1;
            short8 v = {0,0,0,0,0,0,0,0};
            if ((unsigned)gh < HH && (unsigned)gw < WW) {
                const float* sp = in + ((size_t)(b*C + g*8)*HW + gh*WW + gw);
#pragma unroll
                for (int k = 0; k < 8; ++k) v[k] = (short)f2bf(sp[k*HW]);
            }
            *(short8*)&tile[px*TS + g*8] = v;
        }
    }
    __syncthreads();

    const int wid = t >> 6, ln = t & 63;
    const int l15 = ln & 15, q = ln >> 4;
    const int ng = wid & 1, wr = wid >> 1;           // oc-half, row-quad

    f32x4 acc[4][2];
#pragma unroll
    for (int mg = 0; mg < 4; ++mg)
#pragma unroll
        for (int nt = 0; nt < 2; ++nt) acc[mg][nt] = (f32x4){0.f,0.f,0.f,0.f};

#pragma unroll
    for (int p = 0; p < 9; ++p) {
        const int dh = p / 3, dw = p % 3;
#pragma unroll
        for (int ks = 0; ks < 2; ++ks) {
            short8 bfrag[2];
#pragma unroll
            for (int nt = 0; nt < 2; ++nt)
                bfrag[nt] = *(const short8*)&wb[((size_t)(p*C) + ng*32 + nt*16 + l15)*C + ks*32 + q*8];
            short8 afrag[4];
#pragma unroll
            for (int mg = 0; mg < 4; ++mg)
                afrag[mg] = *(const short8*)&tile[((wr*4 + mg + dh)*18 + l15 + dw)*TS + ks*32 + q*8];
#pragma unroll
            for (int mg = 0; mg < 4; ++mg)
#pragma unroll
                for (int nt = 0; nt < 2; ++nt)
                    acc[mg][nt] = __builtin_amdgcn_mfma_f32_16x16x32_bf16(
                        afrag[mg], bfrag[nt], acc[mg][nt], 0, 0, 0);
        }
    }

    unsigned short* x0o = outp;
#pragma unroll
    for (int nt = 0; nt < 2; ++nt) {
        const int oc = ng*32 + nt*16 + l15;
        const float bv = bias[oc];
        float s = 0.f;
#pragma unroll
        for (int mg = 0; mg < 4; ++mg) {
            const int hh = h0 + wr*4 + mg;
#pragma unroll
            for (int reg = 0; reg < 4; ++reg) {
                const int wwp = w0 + q*4 + reg;
                const unsigned short sv = f2bf(acc[mg][nt][reg] + bv);
                x0o[((size_t)(b*HW) + hh*WW + wwp)*C + oc] = sv;
                s += bf2f(sv);   // mean of rounded bf16 values (matches old path)
            }
        }
        s += __shfl_xor(s, 16);
        s += __shfl_xor(s, 32);
        if (q == 0) sred[ng][nt][wr][l15] = s;
    }
    __syncthreads();
    if (t < 64) {
        const int g2 = t >> 5, nt2 = (t >> 4) & 1, l2 = t & 15;
        float s = sred[g2][nt2][0][l2] + sred[g2][nt2][1][l2]
                + sred[g2][nt2][2][l2] + sred[g2][nt2][3][l2];
        atomicAdd(&m[b*C + t], s * (1.f/(float)HW));
    }
}

// ---------------------------------------------------------------------------
// convf: 512 threads (8 waves), wave = (wr, ng). in = y bf16 NHWC
// (global_load_lds staging, linear LDS + src-side XOR swizzle) -> out fp32
// NCHW (+bias+residual). SWAPPED MFMA: lane = px-col, reg-axis = oc ->
// contiguous NCHW stores.
// ---------------------------------------------------------------------------
__global__ __launch_bounds__(512, 2) void convf_kernel(
    const unsigned short* __restrict__ in,
    const unsigned short* __restrict__ wb,   // [9][64][64] bf16 (B^T)
    const float* __restrict__ bias,
    const float* __restrict__ res,
    float* __restrict__ outg,
    const unsigned short* __restrict__ zpad)
{
    __shared__ __align__(16) unsigned short tile[NCALL*8*64];  // 41 KB (linear)
    const int b  = blockIdx.z;
    const int h0 = blockIdx.y * 16;
    const int w0 = blockIdx.x * 16;
    const int t  = threadIdx.x;

    stage_tile_nhwc8(in, tile, zpad, b, h0, w0, t);
    __syncthreads();

    const int wid = t >> 6, ln = t & 63;
    const int l15 = ln & 15, q = ln >> 4;
    const int ng = wid & 1, wr = wid >> 1;           // oc-half, row-quad

    f32x4 acc[4][2];
#pragma unroll
    for (int mg = 0; mg < 4; ++mg)
#pragma unroll
        for (int nt = 0; nt < 2; ++nt) acc[mg][nt] = (f32x4){0.f,0.f,0.f,0.f};

#pragma unroll
    for (int p = 0; p < 9; ++p) {
        const int dh = p / 3, dw = p % 3;
#pragma unroll
        for (int ks = 0; ks < 2; ++ks) {
            short8 bfrag[2];
#pragma unroll
            for (int nt = 0; nt < 2; ++nt)
                bfrag[nt] = *(const short8*)&wb[((size_t)(p*C) + ng*32 + nt*16 + l15)*C + ks*32 + q*8];
            short8 afrag[4];
#pragma unroll
            for (int mg = 0; mg < 4; ++mg) {
                const int px = (wr*4 + mg + dh)*18 + l15 + dw;
                const int o  = (ks*4 + q) ^ (px & 7);
                afrag[mg] = *(const short8*)&tile[px*64 + o*8];
            }
#pragma unroll
            for (int mg = 0; mg < 4; ++mg)
#pragma unroll
                for (int nt = 0; nt < 2; ++nt)   // swapped: lane = px-col
                    acc[mg][nt] = __builtin_amdgcn_mfma_f32_16x16x32_bf16(
                        bfrag[nt], afrag[mg], acc[mg][nt], 0, 0, 0);
        }
    }

    // Swapped-D epilogue: oc = ng*32 + nt*16 + q*4 + reg, px-col = l15.
#pragma unroll
    for (int mg = 0; mg < 4; ++mg) {
        const int hh = h0 + wr*4 + mg;
#pragma unroll
        for (int nt = 0; nt < 2; ++nt) {
            const f32x4 bv4 = *(const f32x4*)&bias[ng*32 + nt*16 + q*4];
#pragma unroll
            for (int reg = 0; reg < 4; ++reg) {
                const int oc = ng*32 + nt*16 + q*4 + reg;
                const size_t base = (size_t)(b*C + oc)*HW + hh*WW + w0 + l15;
                outg[base] = acc[mg][nt][reg] + bv4[reg] + res[base];
            }
        }
    }
}

// ---------------------------------------------------------------------------
// Fused: 512 threads (8 waves). x0 staged via global_load_lds (linear +
// src-swizzle); phase 1 splits channels by thread parity (round-2 verified
// mapping); A-matrix bf16 XOR-swizzled in alds; phase 2 = SWAPPED-operand
// MFMA filter GEMM, 2 px-rows/wave, unroll-1 j-loop (no spill); leaky;
// swizzled ybuf -> coalesced NHWC store.
// ---------------------------------------------------------------------------
__global__ __launch_bounds__(512, 2) void fused_kernel(
    const unsigned short* __restrict__ x0,
    const float* __restrict__ w1, const float* __restrict__ b1,
    const float* __restrict__ w2, const float* __restrict__ b2,
    const unsigned short* __restrict__ wb3,  // [9][64][64] bf16 (B^T, n'=j*64+oc)
    const float* __restrict__ b3r,           // [9][64]
    const float* __restrict__ m,
    unsigned short* __restrict__ y,
    const unsigned short* __restrict__ zpad)
{
    __shared__ __align__(16) unsigned short tile[NCALL*8*64];  // 41 KB
    __shared__ __align__(16) unsigned short alds[256*64];      // 32 KB; reused as ybuf
    __shared__ __align__(16) float att[64];                    // 256 B
    const int b  = blockIdx.z;
    const int h0 = blockIdx.y * 16;
    const int w0 = blockIdx.x * 16;
    const int t  = threadIdx.x;

    if (t < 64) {   // per-block ECA + b1 term (uniform over pixels)
        const float mc = m[b*C + t];
        const float mp = (t > 0)  ? m[b*C + t - 1] : 0.f;
        const float mn = (t < 63) ? m[b*C + t + 1] : 0.f;
        att[t] = b1[t] + fmaf(w2[0], mp, fmaf(w2[1], mc, fmaf(w2[2], mn, b2[0])));
    }
    stage_tile_nhwc8(x0, tile, zpad, b, h0, w0, t);
    __syncthreads();

    // ---- phase 1: depthwise + att, half the channels per thread ----
    {
        const int px1 = t >> 1, chalf = t & 1;
        const int r1 = px1 >> 4, c1 = px1 & 15;
        const int sw1 = px1 & 7;
#pragma unroll
        for (int g = 0; g < 4; ++g) {
            const int kg = chalf*4 + g;              // channel octet 0..7
            float dw8[8];
#pragma unroll
            for (int k = 0; k < 8; ++k) dw8[k] = 0.f;
#pragma unroll
            for (int j = 0; j < 9; ++j) {
                const int px = (r1 + j/3)*18 + c1 + (j%3);
                const short8 v = *(const short8*)&tile[px*64 + ((kg ^ (px&7))*8)];
#pragma unroll
                for (int k = 0; k < 8; ++k)
                    dw8[k] = fmaf(w1[(kg*8 + k)*9 + j],
                                  bf2f((unsigned short)v[k]), dw8[k]);
            }
            short8 ov;
#pragma unroll
            for (int k = 0; k < 8; ++k)
                ov[k] = (short)f2bf(dw8[k] + att[kg*8 + k]);
            *(short8*)&alds[px1*64 + ((kg ^ sw1) * 8)] = ov;
        }
    }
    __syncthreads();

    const int wid = t >> 6, ln = t & 63;
    const int l15 = ln & 15, q = ln >> 4;

    // ---- preload a-frags once (2 px-rows per wave) ----
    short8 afrag[2][2];
#pragma unroll
    for (int mg = 0; mg < 2; ++mg) {
        const int px = (wid*2 + mg)*16 + l15;
        const int sw = px & 7;
#pragma unroll
        for (int ks = 0; ks < 2; ++ks)
            afrag[mg][ks] = *(const short8*)&alds[px*64 + (((ks*4 + q) ^ sw) * 8)];
    }

    f32x4 y_acc[2][4];   // [mg][ntoc]; lane: px-col=l15, oc = ntoc*16 + q*4 + reg
#pragma unroll
    for (int mg = 0; mg < 2; ++mg)
#pragma unroll
        for (int nt = 0; nt < 4; ++nt) y_acc[mg][nt] = (f32x4){0.f,0.f,0.f,0.f};

    // ---- phase 2: SWAPPED operands; j runtime loop bounds the live window ----
#pragma unroll 1
    for (int j = 0; j < 9; ++j) {
        const int dh = j / 3, dw = j - dh*3;
#pragma unroll
        for (int ntoc = 0; ntoc < 4; ++ntoc) {
            const short8 bf0 = *(const short8*)&wb3[((size_t)(j*64 + ntoc*16 + l15))*64 + q*8];
            const short8 bf1 = *(const short8*)&wb3[((size_t)(j*64 + ntoc*16 + l15))*64 + 32 + q*8];
            const f32x4 b3v4 = *(const f32x4*)&b3r[j*64 + ntoc*16 + q*4];
#pragma unroll
            for (int mg = 0; mg < 2; ++mg) {
                f32x4 a = b3v4;
                a = __builtin_amdgcn_mfma_f32_16x16x32_bf16(bf0, afrag[mg][0], a, 0, 0, 0);
                a = __builtin_amdgcn_mfma_f32_16x16x32_bf16(bf1, afrag[mg][1], a, 0, 0, 0);
                const int px = (wid*2 + mg + dh)*18 + l15 + dw;
                const int o  = (ntoc*2 + (q >> 1)) ^ (px & 7);
                const us4 pv = *(const us4*)&tile[px*64 + o*8 + (q & 1)*4];
#pragma unroll
                for (int reg = 0; reg < 4; ++reg)
                    y_acc[mg][ntoc][reg] = fmaf(a[reg], bf2f(pv[reg]), y_acc[mg][ntoc][reg]);
            }
        }
    }

    // ---- leaky + swizzled ybuf (reuse alds) + coalesced NHWC writeout ----
    __syncthreads();                          // all alds reads done
    unsigned short* ybuf = alds;
#pragma unroll
    for (int mg = 0; mg < 2; ++mg) {
        const int rr = wid*2 + mg;
        const int px = rr*16 + l15;
        const int swy = (px & 7) << 1;        // even XOR: keeps 16B pairs intact
#pragma unroll
        for (int ntoc = 0; ntoc < 4; ++ntoc) {
            us4 ov;
#pragma unroll
            for (int reg = 0; reg < 4; ++reg) {
                float v = y_acc[mg][ntoc][reg];
                v = (v >= 0.f) ? v : 0.2f * v;
                ov[reg] = f2bf(v);
            }
            const int slot = (ntoc*4 + q) ^ swy;
            *(us4*)&ybuf[px*64 + slot*4] = ov;
        }
    }
    __syncthreads();
    for (int id = t; id < 2048; id += 512) {
        int px = id >> 3, g = id & 7;
        const int swy = (px & 7) << 1;
        short8 v = *(const short8*)&ybuf[px*64 + ((2*g) ^ swy)*4];
        int rr = px >> 4, cw = px & 15;
        *(short8*)&y[((size_t)(b*HW) + (h0+rr)*WW + (w0+cw))*C + g*8] = v;
    }
}

extern "C" void kernel_launch(void* const* d_in, const int* in_sizes, int n_in,
                              void* d_out, int out_size, void* d_ws, size_t ws_size,
                              hipStream_t stream) {
    const float* x  = (const float*)d_in[0];
    const float* w0 = (const float*)d_in[1];
    const float* b0 = (const float*)d_in[2];
    const float* w1 = (const float*)d_in[3];
    const float* b1 = (const float*)d_in[4];
    const float* w2 = (const float*)d_in[5];
    const float* b2 = (const float*)d_in[6];
    const float* w3 = (const float*)d_in[7];
    const float* b3 = (const float*)d_in[8];
    const float* wf = (const float*)d_in[9];
    const float* bf = (const float*)d_in[10];
    float* out = (float*)d_out;

    unsigned short* x0  = (unsigned short*)d_ws;            // [B,H,W,C] bf16
    unsigned short* y   = x0 + (size_t)BB*HW*C;             // [B,H,W,C] bf16
    float*          m   = (float*)(y + (size_t)BB*HW*C);    // [B*C]
    unsigned short* wb0 = (unsigned short*)(m + BB*C);      // [9][64][64] bf16
    unsigned short* wbf = wb0 + 9*C*C;
    unsigned short* wb3 = wbf + 9*C*C;                      // [9][64][64] bf16
    float*          b3r = (float*)(wb3 + 9*C*C);            // [9][64]
    unsigned short* zpad = (unsigned short*)(b3r + 9*C);    // 128 ushort zeros

    prep_kernel<<<128, 256, 0, stream>>>(w0, wf, w3, b3, wb0, wbf, wb3, b3r, m, zpad);
    conv0_kernel<<<dim3(8,8,8), 512, 0, stream>>>(x, wb0, b0, x0, m);
    fused_kernel<<<dim3(8,8,8), 512, 0, stream>>>(x0, w1, b1, w2, b2, wb3, b3r, m, y, zpad);
    convf_kernel<<<dim3(8,8,8), 512, 0, stream>>>(y, wbf, bf, x, out, zpad);
}

// Round 13
// 205.316 us; speedup vs baseline: 1.0949x; 1.0949x over previous
//
#include <hip/hip_runtime.h>

#define BB 8
#define C 64
#define HH 128
#define WW 128
#define HW (HH*WW)

#define TS 72        // LDS channel stride (ushorts) for halo tile
#define NPX 324      // 18*18 halo tile pixels

typedef __attribute__((ext_vector_type(8))) short short8;
typedef __attribute__((ext_vector_type(4))) unsigned short us4;
typedef __attribute__((ext_vector_type(4))) float f32x4;

__device__ inline unsigned short f2bf(float f) {
    union { float f; unsigned u; } v; v.f = f;
    unsigned r = v.u + 0x7fff + ((v.u >> 16) & 1);   // RNE
    return (unsigned short)(r >> 16);
}
__device__ inline float bf2f(unsigned short h) {
    union { unsigned u; float f; } v; v.u = ((unsigned)h) << 16;
    return v.f;
}

// ---------------------------------------------------------------------------
// Prep: wb[p][oc][ci] (B^T bf16) for conv0/convf; wb3[j][oc][k] bf16 and
// b3r[j][oc] for the dynamic-filter GEMM; zero m. 128 blocks.
// ---------------------------------------------------------------------------
__global__ __launch_bounds__(256) void prep_kernel(
    const float* __restrict__ w0, const float* __restrict__ wf,
    const float* __restrict__ w3, const float* __restrict__ b3,
    unsigned short* __restrict__ wb0, unsigned short* __restrict__ wbf,
    unsigned short* __restrict__ wb3, float* __restrict__ b3r,
    float* __restrict__ m)
{
    const int t = blockIdx.x * 256 + threadIdx.x;
    for (int i = t; i < C*C*9; i += 128*256) {
        int p = i % 9; int rest = i / 9; int ci = rest % C; int oc = rest / C;
        wb0[(p*C + oc)*C + ci] = f2bf(w0[i]);
        wbf[(p*C + oc)*C + ci] = f2bf(wf[i]);
    }
    for (int i = t; i < 9*C*C; i += 128*256) {       // dst index: ((j*64+oc)*64+k)
        int j = i >> 12, oc = (i >> 6) & 63, k = i & 63;
        wb3[i] = f2bf(w3[(oc*9 + j)*C + k]);
    }
    for (int i = t; i < 9*C; i += 128*256) {         // b3r[j*64+oc] = b3[oc*9+j]
        int j = i >> 6, oc = i & 63;
        b3r[i] = b3[oc*9 + j];
    }
    for (int i = t; i < BB*C; i += 128*256) m[i] = 0.f;
}

// ---------------------------------------------------------------------------
// MFMA implicit-GEMM 3x3 conv. 16x16 px tile, 256 threads (4 waves), all 64
// oc per wave, full p-loop unroll, no min-waves bound (~248 VGPR, no spill).
// Best-measured configuration (round 8, total 207.4 us).
// FIRST:  in = x fp32 NCHW -> out = x0 bf16 NHWC (+bias) + fused mean -> m
// !FIRST: in = y bf16 NHWC -> out = fp32 NCHW (+bias+residual x)
// ---------------------------------------------------------------------------
template<bool FIRST>
__global__ __launch_bounds__(256) void conv_mfma_kernel(
    const void* __restrict__ in,
    const unsigned short* __restrict__ wb,   // [9][64][64] bf16 (B^T)
    const float* __restrict__ bias,
    const float* __restrict__ res,
    void* __restrict__ outp,
    float* __restrict__ m)
{
    __shared__ __align__(16) unsigned short tile[NPX*TS];  // 46.7 KB
    __shared__ __align__(16) float sred[4][4][16];         // 1 KB (mean reduce)
    const int b  = blockIdx.z;
    const int h0 = blockIdx.y * 16;
    const int w0 = blockIdx.x * 16;
    const int t  = threadIdx.x;

    {
        const int pxi = t & 31, g = t >> 5;          // g = channel octet
        for (int px = pxi; px < NPX; px += 32) {
            int th = px / 18, tw = px - th*18;
            int gh = h0 + th - 1, gw = w0 + tw - 1;
            short8 v = {0,0,0,0,0,0,0,0};
            if ((unsigned)gh < HH && (unsigned)gw < WW) {
                if (FIRST) {
                    const float* sp = (const float*)in
                        + ((size_t)(b*C + g*8)*HW + gh*WW + gw);
#pragma unroll
                    for (int k = 0; k < 8; ++k) v[k] = (short)f2bf(sp[k*HW]);
                } else {
                    v = *(const short8*)((const unsigned short*)in
                        + ((size_t)(b*HW) + gh*WW + gw)*C + g*8);
                }
            }
            *(short8*)&tile[px*TS + g*8] = v;
        }
    }
    __syncthreads();

    const int wid = t >> 6, ln = t & 63;
    const int l15 = ln & 15, q = ln >> 4;

    f32x4 acc[4][4];
#pragma unroll
    for (int mg = 0; mg < 4; ++mg)
#pragma unroll
        for (int nt = 0; nt < 4; ++nt) acc[mg][nt] = (f32x4){0.f,0.f,0.f,0.f};

#pragma unroll
    for (int p = 0; p < 9; ++p) {
        const int dh = p / 3, dw = p % 3;
#pragma unroll
        for (int ks = 0; ks < 2; ++ks) {
            short8 bfrag[4];
#pragma unroll
            for (int nt = 0; nt < 4; ++nt)
                bfrag[nt] = *(const short8*)&wb[((size_t)(p*C) + nt*16 + l15)*C + ks*32 + q*8];
            short8 afrag[4];
#pragma unroll
            for (int mg = 0; mg < 4; ++mg) {
                const int r = wid*4 + mg;
                afrag[mg] = *(const short8*)&tile[((r+dh)*18 + l15 + dw)*TS + ks*32 + q*8];
            }
#pragma unroll
            for (int mg = 0; mg < 4; ++mg)
#pragma unroll
                for (int nt = 0; nt < 4; ++nt)
                    acc[mg][nt] = __builtin_amdgcn_mfma_f32_16x16x32_bf16(
                        afrag[mg], bfrag[nt], acc[mg][nt], 0, 0, 0);
        }
    }

    if (FIRST) {
        unsigned short* x0o = (unsigned short*)outp;
#pragma unroll
        for (int nt = 0; nt < 4; ++nt) {
            const int oc = nt*16 + l15;
            const float bv = bias[oc];
            float s = 0.f;
#pragma unroll
            for (int mg = 0; mg < 4; ++mg) {
                const int hh = h0 + wid*4 + mg;
#pragma unroll
                for (int reg = 0; reg < 4; ++reg) {
                    const int wwp = w0 + q*4 + reg;
                    const unsigned short sv = f2bf(acc[mg][nt][reg] + bv);
                    x0o[((size_t)(b*HW) + hh*WW + wwp)*C + oc] = sv;
                    s += bf2f(sv);   // mean of rounded bf16 values (matches old path)
                }
            }
            s += __shfl_xor(s, 16);  // sum over q (px-col groups)
            s += __shfl_xor(s, 32);
            if (q == 0) sred[wid][nt][l15] = s;
        }
        __syncthreads();
        if (t < 64) {
            float s = sred[0][t >> 4][t & 15] + sred[1][t >> 4][t & 15]
                    + sred[2][t >> 4][t & 15] + sred[3][t >> 4][t & 15];
            atomicAdd(&m[b*C + t], s * (1.f/(float)HW));
        }
    } else {
        float* outg = (float*)outp;
#pragma unroll
        for (int mg = 0; mg < 4; ++mg) {
            const int hh = h0 + wid*4 + mg;
#pragma unroll
            for (int nt = 0; nt < 4; ++nt) {
                const int oc = nt*16 + l15;
                const float bv = bias[oc];
                const size_t base = (size_t)(b*C + oc)*HW + hh*WW + w0 + q*4;
                const float4 rv = *(const float4*)&res[base];
                float4 ov;
                ov.x = acc[mg][nt][0] + bv + rv.x;
                ov.y = acc[mg][nt][1] + bv + rv.y;
                ov.z = acc[mg][nt][2] + bv + rv.z;
                ov.w = acc[mg][nt][3] + bv + rv.w;
                *(float4*)&outg[base] = ov;
            }
        }
    }
}

// ---------------------------------------------------------------------------
// Fused (88 VGPR / ~44 us, best-measured): depthwise3x3 + ECA (att[64]) ->
// LDS A-matrix (XOR-swizzled); SWAPPED-operand MFMA filter GEMM (reg-axis
// walks oc -> us4 vector consume from resident tile); j-loop unroll-capped
// to keep hoisted loads inside the register budget; leaky; swizzled ybuf ->
// coalesced NHWC bf16 store.
// ---------------------------------------------------------------------------
__global__ __launch_bounds__(256) void fused_kernel(
    const unsigned short* __restrict__ x0,
    const float* __restrict__ w1, const float* __restrict__ b1,
    const float* __restrict__ w2, const float* __restrict__ b2,
    const unsigned short* __restrict__ wb3,  // [9][64][64] bf16 (B^T, n'=j*64+oc)
    const float* __restrict__ b3r,           // [9][64]
    const float* __restrict__ m,
    unsigned short* __restrict__ y)
{
    __shared__ __align__(16) unsigned short tile[NPX*TS];   // 46656 B
    __shared__ __align__(16) unsigned short alds[256*64];   // 32768 B; reused as ybuf
    __shared__ __align__(16) float att[64];                 // 256 B
    const int b  = blockIdx.z;
    const int h0 = blockIdx.y * 16;
    const int w0 = blockIdx.x * 16;
    const int t  = threadIdx.x;

    if (t < 64) {   // per-block ECA + b1 term (uniform over pixels)
        const float mc = m[b*C + t];
        const float mp = (t > 0)  ? m[b*C + t - 1] : 0.f;
        const float mn = (t < 63) ? m[b*C + t + 1] : 0.f;
        att[t] = b1[t] + fmaf(w2[0], mp, fmaf(w2[1], mc, fmaf(w2[2], mn, b2[0])));
    }
    {
        const int pxi = t & 31, g = t >> 5;
        for (int px = pxi; px < NPX; px += 32) {
            int th = px / 18, tw = px - th*18;
            int gh = h0 + th - 1, gw = w0 + tw - 1;
            short8 v = {0,0,0,0,0,0,0,0};
            if ((unsigned)gh < HH && (unsigned)gw < WW)
                v = *(const short8*)&x0[((size_t)(b*HW) + gh*WW + gw)*C + g*8];
            *(short8*)&tile[px*TS + g*8] = v;
        }
    }
    __syncthreads();

    const int r = t >> 4, cc = t & 15;
    const unsigned short* tbase = tile + (r*18 + cc)*TS;

    // ---- phase 1: depthwise + att -> outv[64] ----
    float outv[64];
#pragma unroll
    for (int g = 0; g < 8; ++g) {
        float dw8[8];
#pragma unroll
        for (int k = 0; k < 8; ++k) dw8[k] = 0.f;
#pragma unroll
        for (int j = 0; j < 9; ++j) {
            short8 v = *(const short8*)&tbase[((j/3)*18 + (j%3))*TS + g*8];
#pragma unroll
            for (int k = 0; k < 8; ++k)
                dw8[k] = fmaf(w1[(g*8+k)*9 + j], bf2f((unsigned short)v[k]), dw8[k]);
        }
#pragma unroll
        for (int k = 0; k < 8; ++k) {
            const int c = g*8 + k;
            outv[c] = dw8[k] + att[c];
        }
    }

    // ---- write A[px][k] bf16 to LDS, XOR-swizzled 16B groups ----
    {
        const int sw = t & 7;
#pragma unroll
        for (int g = 0; g < 8; ++g) {
            short8 v;
#pragma unroll
            for (int k = 0; k < 8; ++k) v[k] = (short)f2bf(outv[g*8 + k]);
            *(short8*)&alds[t*64 + ((g ^ sw) * 8)] = v;
        }
    }
    __syncthreads();

    const int wid = t >> 6, ln = t & 63;
    const int l15 = ln & 15, q = ln >> 4;

    // ---- preload a-frags once (reused across all 36 n-tiles) ----
    short8 afrag[4][2];
#pragma unroll
    for (int mg = 0; mg < 4; ++mg) {
        const int px = (wid*4 + mg)*16 + l15;
        const int sw = px & 7;
#pragma unroll
        for (int ks = 0; ks < 2; ++ks)
            afrag[mg][ks] = *(const short8*)&alds[px*64 + (((ks*4 + q) ^ sw) * 8)];
    }

    f32x4 y_acc[4][4];   // [mg][ntoc]; lane: px-col=l15, oc = ntoc*16 + q*4 + reg
#pragma unroll
    for (int mg = 0; mg < 4; ++mg)
#pragma unroll
        for (int nt = 0; nt < 4; ++nt) y_acc[mg][nt] = (f32x4){0.f,0.f,0.f,0.f};

    // ---- phase 2: SWAPPED operands; j runtime loop bounds the live window ----
#pragma unroll 1
    for (int j = 0; j < 9; ++j) {
        const int dh = j / 3, dw = j - dh*3;
#pragma unroll
        for (int ntoc = 0; ntoc < 4; ++ntoc) {
            const short8 bf0 = *(const short8*)&wb3[((size_t)(j*64 + ntoc*16 + l15))*64 + q*8];
            const short8 bf1 = *(const short8*)&wb3[((size_t)(j*64 + ntoc*16 + l15))*64 + 32 + q*8];
            const f32x4 b3v4 = *(const f32x4*)&b3r[j*64 + ntoc*16 + q*4];
#pragma unroll
            for (int mg = 0; mg < 4; ++mg) {
                f32x4 a = b3v4;
                a = __builtin_amdgcn_mfma_f32_16x16x32_bf16(bf0, afrag[mg][0], a, 0, 0, 0);
                a = __builtin_amdgcn_mfma_f32_16x16x32_bf16(bf1, afrag[mg][1], a, 0, 0, 0);
                const int rr = wid*4 + mg;
                const us4 pv = *(const us4*)
                    &tile[((rr+dh)*18 + l15 + dw)*TS + ntoc*16 + q*4];
#pragma unroll
                for (int reg = 0; reg < 4; ++reg)
                    y_acc[mg][ntoc][reg] = fmaf(a[reg], bf2f(pv[reg]), y_acc[mg][ntoc][reg]);
            }
        }
    }

    // ---- leaky + swizzled ybuf (reuse alds) + coalesced NHWC writeout ----
    __syncthreads();                          // all alds reads done
    unsigned short* ybuf = alds;
#pragma unroll
    for (int mg = 0; mg < 4; ++mg) {
        const int rr = wid*4 + mg;
        const int px = rr*16 + l15;
        const int swy = (px & 7) << 1;        // even XOR: keeps 16B pairs intact
#pragma unroll
        for (int ntoc = 0; ntoc < 4; ++ntoc) {
            us4 ov;
#pragma unroll
            for (int reg = 0; reg < 4; ++reg) {
                float v = y_acc[mg][ntoc][reg];
                v = (v >= 0.f) ? v : 0.2f * v;
                ov[reg] = f2bf(v);
            }
            const int slot = (ntoc*4 + q) ^ swy;
            *(us4*)&ybuf[px*64 + slot*4] = ov;
        }
    }
    __syncthreads();
    for (int id = t; id < 2048; id += 256) {
        int px = id >> 3, g = id & 7;
        const int swy = (px & 7) << 1;
        short8 v = *(const short8*)&ybuf[px*64 + ((2*g) ^ swy)*4];
        int rr = px >> 4, cw = px & 15;
        *(short8*)&y[((size_t)(b*HW) + (h0+rr)*WW + (w0+cw))*C + g*8] = v;
    }
}

extern "C" void kernel_launch(void* const* d_in, const int* in_sizes, int n_in,
                              void* d_out, int out_size, void* d_ws, size_t ws_size,
                              hipStream_t stream) {
    const float* x  = (const float*)d_in[0];
    const float* w0 = (const float*)d_in[1];
    const float* b0 = (const float*)d_in[2];
    const float* w1 = (const float*)d_in[3];
    const float* b1 = (const float*)d_in[4];
    const float* w2 = (const float*)d_in[5];
    const float* b2 = (const float*)d_in[6];
    const float* w3 = (const float*)d_in[7];
    const float* b3 = (const float*)d_in[8];
    const float* wf = (const float*)d_in[9];
    const float* bf = (const float*)d_in[10];
    float* out = (float*)d_out;

    unsigned short* x0  = (unsigned short*)d_ws;            // [B,H,W,C] bf16
    unsigned short* y   = x0 + (size_t)BB*HW*C;             // [B,H,W,C] bf16
    float*          m   = (float*)(y + (size_t)BB*HW*C);    // [B*C]
    unsigned short* wb0 = (unsigned short*)(m + BB*C);      // [9][64][64] bf16
    unsigned short* wbf = wb0 + 9*C*C;
    unsigned short* wb3 = wbf + 9*C*C;                      // [9][64][64] bf16
    float*          b3r = (float*)(wb3 + 9*C*C);            // [9][64]

    prep_kernel<<<128, 256, 0, stream>>>(w0, wf, w3, b3, wb0, wbf, wb3, b3r, m);
    conv_mfma_kernel<true><<<dim3(8,8,8), 256, 0, stream>>>(x, wb0, b0, nullptr, x0, m);
    fused_kernel<<<dim3(8,8,8), 256, 0, stream>>>(x0, w1, b1, w2, b2, wb3, b3r, m, y);
    conv_mfma_kernel<false><<<dim3(8,8,8), 256, 0, stream>>>(y, wbf, bf, x, out, nullptr);
}